// Round 19
// baseline (309.097 us; speedup 1.0000x reference)
//
#include <hip/hip_runtime.h>

#define KC 24
#define DC 128
#define TPB 256
#define NROWS 524288
#define CBS 132            // cb_s row stride (16B aligned)
#define WSTR 24            // w_s row stride: 96B = 16B-aligned, LDS < 40KB -> 4 blocks/CU
#define NSLICE 8

#define NB_EBIN 1024
#define ROWS_PER_EBIN (NROWS / NB_EBIN)   // 512 rows/block, 128/wave
#define PSTR 3104
#define FINAL_OFF (NB_EBIN * PSTR)
#define LOSS_OFF (FINAL_OFF + PSTR)
#define CTR_OFF (LOSS_OFF + NSLICE)
#define RB 32
#define NRED_BLK ((KC * DC + KC + TPB - 1) / TPB)   // 13
#define TOTAL_RED (NRED_BLK * (NB_EBIN / RB))        // 13*32 = 416

typedef float vfloat2 __attribute__((ext_vector_type(2)));
typedef float vfloat4 __attribute__((ext_vector_type(4)));

__device__ __forceinline__ void nt_store2(float* p, float x, float y) {
    vfloat2 v; v.x = x; v.y = y;
    __builtin_nontemporal_store(v, (vfloat2*)p);
}
__device__ __forceinline__ void nt_store4(float* p, float4 q) {
    vfloat4 v; v.x = q.x; v.y = q.y; v.z = q.z; v.w = q.w;
    __builtin_nontemporal_store(v, (vfloat4*)p);
}

__global__ void vq_zero(float* __restrict__ acc) {
    int i = blockIdx.x * blockDim.x + threadIdx.x;
    if (i < PSTR + NSLICE + 1) acc[FINAL_OFF + i] = 0.0f;   // finals + loss + counter
}

// ---- Kernel 1: compute (per-thread) + emit (per-wave, coalesced, NT stores) ----
__global__ __launch_bounds__(TPB, 4) void vq_main(
    const float* __restrict__ z_e, const float* __restrict__ cb,
    float* __restrict__ o_soft, float* __restrict__ o_hard,
    float* __restrict__ o_idx, float* __restrict__ o_w,
    float* __restrict__ acc)
{
    __shared__ float cb_s[KC][CBS];
    __shared__ float wn_s[KC];
    __shared__ float w_s[4][64][WSTR];
    __shared__ int   idx_s[TPB];

    const int tid = threadIdx.x;
    const int wv  = tid >> 6;
    const int l   = tid & 63;

    #pragma unroll 1
    for (int i = tid; i < KC * DC; i += TPB)
        cb_s[i >> 7][i & (DC - 1)] = cb[i];
    __syncthreads();
    if (tid < KC) {
        float s = 0.0f;
        #pragma unroll 1
        for (int d = 0; d < DC; ++d) s = fmaf(cb_s[tid][d], cb_s[tid][d], s);
        wn_s[tid] = s;
    }
    __syncthreads();

    const int row = blockIdx.x * TPB + tid;
    const float* zp = z_e + (size_t)row * DC;

    // ---- Phase 1: per-thread distances/argmin/softmax ----
    float dv[KC];
    #pragma unroll
    for (int k = 0; k < KC; ++k) dv[k] = 0.0f;
    float zn = 0.0f;

    #pragma unroll 2
    for (int c = 0; c < 4; ++c) {
        float4 a[8];
        #pragma unroll
        for (int i = 0; i < 8; ++i)
            a[i] = *(const float4*)(zp + c * 32 + 4 * i);
        #pragma unroll
        for (int i = 0; i < 8; ++i)
            zn = fmaf(a[i].x, a[i].x, fmaf(a[i].y, a[i].y,
                 fmaf(a[i].z, a[i].z, fmaf(a[i].w, a[i].w, zn))));
        #pragma unroll
        for (int k = 0; k < KC; ++k) {
            float s = dv[k];
            #pragma unroll
            for (int i = 0; i < 8; ++i) {
                const float4 wvv = *(const float4*)(&cb_s[k][c * 32 + 4 * i]);
                s = fmaf(a[i].x, wvv.x, fmaf(a[i].y, wvv.y,
                    fmaf(a[i].z, wvv.z, fmaf(a[i].w, wvv.w, s))));
            }
            dv[k] = s;
        }
    }

    int idx = 0;
    float best = 3.4e38f;
    #pragma unroll
    for (int k = 0; k < KC; ++k) {
        float d = (zn - 2.0f * dv[k]) + wn_s[k];
        dv[k] = d;
        if (d < best) { best = d; idx = k; }
    }
    float ssum = 0.0f;
    #pragma unroll
    for (int k = 0; k < KC; ++k) {
        float e = __expf(best - dv[k]);
        dv[k] = e;
        ssum += e;
    }
    const float inv = 1.0f / ssum;
    #pragma unroll
    for (int k = 0; k < KC; ++k) dv[k] *= inv;   // weights

    // stage weights + idx for the emit phase
    #pragma unroll
    for (int q = 0; q < 6; ++q)
        *(float4*)(&w_s[wv][l][4 * q]) =
            make_float4(dv[4*q], dv[4*q+1], dv[4*q+2], dv[4*q+3]);
    idx_s[tid] = idx;
    o_idx[row] = (float)idx;                      // coalesced

    {
        float loss_acc = best;   // min-dist identity
        #pragma unroll
        for (int off = 32; off > 0; off >>= 1)
            loss_acc += __shfl_down(loss_acc, off);
        if (l == 0)
            atomicAdd(acc + LOSS_OFF + (blockIdx.x & (NSLICE - 1)), loss_acc);
    }
    __syncthreads();

    // ---- Phase 2: per-wave emit, lane-consecutive, nontemporal ----
    const int base2 = blockIdx.x * TPB + wv * 64;   // wave's first row
    const int d2 = 2 * l;
    float2 cbr[KC];
    #pragma unroll
    for (int k = 0; k < KC; ++k)
        cbr[k] = *(const float2*)(&cb_s[k][d2]);

    #pragma unroll 2
    for (int j = 0; j < 64; ++j) {
        const int r = base2 + j;
        const int ic = idx_s[wv * 64 + j];
        float wk[KC];
        #pragma unroll
        for (int q = 0; q < 6; ++q) {
            const float4 wq = *(const float4*)(&w_s[wv][j][4 * q]);  // uniform
            wk[4*q+0] = wq.x; wk[4*q+1] = wq.y;
            wk[4*q+2] = wq.z; wk[4*q+3] = wq.w;
        }
        float q0 = 0.0f, q1 = 0.0f;
        #pragma unroll
        for (int k = 0; k < KC; ++k) {
            q0 = fmaf(wk[k], cbr[k].x, q0);
            q1 = fmaf(wk[k], cbr[k].y, q1);
        }
        nt_store2(o_soft + (size_t)r * DC + d2, q0, q1);
        const float2 h2 = *(const float2*)(&cb_s[ic][d2]);
        nt_store2(o_hard + (size_t)r * DC + d2, h2.x, h2.y);
    }

    // weights out: 6 coalesced float4 per wave (nontemporal)
    #pragma unroll
    for (int i = 0; i < 6; ++i) {
        const int fo = i * 64 + l;
        const int jr = fo / 6, c = fo % 6;
        const float4 v = *(const float4*)(&w_s[wv][jr][4 * c]);
        nt_store4(o_w + (size_t)base2 * KC + 4 * fo, v);
    }
}

// ---- Kernel 2: ebin — wave-private LDS bins, non-atomic RMW, 16-deep MLP ----
__global__ __launch_bounds__(TPB) void vq_ebin(
    const float* __restrict__ z_e, const float* __restrict__ o_idx,
    float* __restrict__ acc)
{
    __shared__ float eb[4][KC][DC];    // 48 KB: wave-private bins
    __shared__ float cnt_sh[4][KC];

    const int tid = threadIdx.x;
    const int w   = tid >> 6;
    const int l   = tid & 63;
    const int d2  = 2 * l;

    #pragma unroll 1
    for (int i = l; i < KC * DC / 2; i += 64)
        ((float2*)&eb[w][0][0])[i] = make_float2(0.0f, 0.0f);
    if (l < KC) cnt_sh[w][l] = 0.0f;

    const int r0 = blockIdx.x * ROWS_PER_EBIN + w * (ROWS_PER_EBIN / 4);

    #pragma unroll 1
    for (int rb = 0; rb < ROWS_PER_EBIN / 4; rb += 16) {
        float2 v[16];
        float  fid[16];
        #pragma unroll
        for (int j = 0; j < 16; ++j)
            v[j] = *(const float2*)(z_e + (size_t)(r0 + rb + j) * DC + d2);
        #pragma unroll
        for (int j = 0; j < 16; ++j)
            fid[j] = o_idx[r0 + rb + j];
        #pragma unroll
        for (int j = 0; j < 16; ++j) {
            const int ic = (int)fid[j];
            float2 cur = *(float2*)(&eb[w][ic][d2]);    // wave-uniform row
            cur.x += v[j].x;
            cur.y += v[j].y;
            *(float2*)(&eb[w][ic][d2]) = cur;
            if (l == 0) cnt_sh[w][ic] += 1.0f;
        }
    }
    __syncthreads();

    float* part = acc + (size_t)blockIdx.x * PSTR;
    #pragma unroll 1
    for (int i = tid; i < KC * DC; i += TPB) {
        const int k = i >> 7, d = i & (DC - 1);
        part[i] = (eb[0][k][d] + eb[1][k][d]) + (eb[2][k][d] + eb[3][k][d]);
    }
    if (tid < KC)
        part[KC * DC + tid] = (cnt_sh[0][tid] + cnt_sh[1][tid])
                            + (cnt_sh[2][tid] + cnt_sh[3][tid]);
}

// ---- Kernel 3: reduce partials + last-block epilogue ----
__global__ void vq_finale(
    const float* __restrict__ z_e, const float* __restrict__ ema_cs,
    const float* __restrict__ ema_es, const int* __restrict__ rand_idx,
    float* __restrict__ acc,
    float* __restrict__ o_loss, float* __restrict__ o_cbn,
    float* __restrict__ o_ecs, float* __restrict__ o_ees)
{
    const int tid = threadIdx.x;
    const int i = blockIdx.x * TPB + tid;
    if (i < KC * DC + KC) {
        const int b0 = blockIdx.y * RB;
        float s0 = 0.0f, s1 = 0.0f, s2 = 0.0f, s3 = 0.0f;
        #pragma unroll 2
        for (int b = b0; b < b0 + RB; b += 4) {
            s0 += acc[(size_t)(b + 0) * PSTR + i];
            s1 += acc[(size_t)(b + 1) * PSTR + i];
            s2 += acc[(size_t)(b + 2) * PSTR + i];
            s3 += acc[(size_t)(b + 3) * PSTR + i];
        }
        atomicAdd(&acc[FINAL_OFF + i], (s0 + s1) + (s2 + s3));
    }

    // arrival: last block of 416 runs the epilogue
    __threadfence();
    __shared__ int last_s;
    if (tid == 0) {
        unsigned int old = atomicAdd((unsigned int*)(acc + CTR_OFF), 1u);
        last_s = (old == TOTAL_RED - 1) ? 1 : 0;
    }
    __syncthreads();
    if (!last_s) return;

    // ---- epilogue (finals read via atomic-load for cross-XCD coherence) ----
    __shared__ float ecs_s[KC], sm_s[KC];
    __shared__ float n_sh;
    float* fin = acc + FINAL_OFF;
    if (tid < KC) {
        float csum = atomicAdd(&fin[KC * DC + tid], 0.0f);
        ecs_s[tid] = 0.95f * ema_cs[tid] + 0.05f * csum;
    }
    __syncthreads();
    if (tid == 0) {
        float n = 0.0f;
        for (int k = 0; k < KC; ++k) n += ecs_s[k];
        n_sh = n;
    }
    __syncthreads();
    if (tid < KC) {
        float n = n_sh;
        sm_s[tid] = (ecs_s[tid] + 1e-5f) / (n + (float)KC * 1e-5f) * n;
    }
    __syncthreads();
    #pragma unroll 1
    for (int j = tid; j < KC * DC; j += TPB) {
        int k = j >> 7, d = j & (DC - 1);
        float esum = atomicAdd(&fin[j], 0.0f);
        float ees = 0.95f * ema_es[j] + 0.05f * esum;
        float cbn = ees / sm_s[k];
        bool dead = ecs_s[k] < 0.1f;
        float rst = z_e[(size_t)rand_idx[k] * DC + d];
        o_cbn[j] = dead ? rst : cbn;
        o_ees[j] = dead ? rst : ees;
    }
    if (tid < KC) o_ecs[tid] = (ecs_s[tid] < 0.1f) ? 1.0f : ecs_s[tid];
    if (tid == 0) {
        float lsum = 0.0f;
        #pragma unroll
        for (int s = 0; s < NSLICE; ++s)
            lsum += atomicAdd(acc + LOSS_OFF + s, 0.0f);
        o_loss[0] = 1.5f * (lsum * (1.0f / 67108864.0f));
    }
}

extern "C" void kernel_launch(void* const* d_in, const int* in_sizes, int n_in,
                              void* d_out, int out_size, void* d_ws, size_t ws_size,
                              hipStream_t stream) {
    const float* z_e    = (const float*)d_in[0];
    const float* cb     = (const float*)d_in[1];
    const float* ema_cs = (const float*)d_in[2];
    const float* ema_es = (const float*)d_in[3];
    const int*   ridx   = (const int*)d_in[4];

    float* out = (float*)d_out;
    float* o_soft = out;                                  // 67108864
    float* o_hard = out + 67108864ll;                     // 67108864
    float* o_idx  = out + 134217728ll;                    // 524288
    float* o_w    = out + 134742016ll;                    // 12582912
    float* o_loss = out + 147324928ll;                    // 1
    float* o_cbn  = out + 147324929ll;                    // 3072
    float* o_ecs  = out + 147328001ll;                    // 24
    float* o_ees  = out + 147328025ll;                    // 3072

    float* acc = (float*)d_ws;

    vq_zero<<<(PSTR + NSLICE + 1 + TPB - 1) / TPB, TPB, 0, stream>>>(acc);
    vq_main<<<NROWS / TPB, TPB, 0, stream>>>(
        z_e, cb, o_soft, o_hard, o_idx, o_w, acc);
    vq_ebin<<<NB_EBIN, TPB, 0, stream>>>(z_e, o_idx, acc);
    {
        dim3 g(NRED_BLK, NB_EBIN / RB);
        vq_finale<<<g, TPB, 0, stream>>>(
            z_e, ema_cs, ema_es, ridx, acc, o_loss, o_cbn, o_ecs, o_ees);
    }
}

// Round 20
// 279.064 us; speedup vs baseline: 1.1076x; 1.1076x over previous
//
#include <hip/hip_runtime.h>

#define KC 24
#define DC 128
#define TPB 256
#define NROWS 524288
#define CBS 132            // cb_s row stride (16B aligned)
#define WSTR 24            // w_s row stride: 96B = 16B-aligned, LDS < 40KB -> 4 blocks/CU
#define NSLICE 8

#define NB_EBIN 1024
#define ROWS_PER_EBIN (NROWS / NB_EBIN)   // 512 rows/block, 128/wave
#define PSTR 3104
#define FINAL_OFF (NB_EBIN * PSTR)
#define LOSS_OFF (FINAL_OFF + PSTR)
#define RB 32

typedef float vfloat2 __attribute__((ext_vector_type(2)));
typedef float vfloat4 __attribute__((ext_vector_type(4)));

__device__ __forceinline__ void nt_store2(float* p, float x, float y) {
    vfloat2 v; v.x = x; v.y = y;
    __builtin_nontemporal_store(v, (vfloat2*)p);
}
__device__ __forceinline__ void nt_store4(float* p, float4 q) {
    vfloat4 v; v.x = q.x; v.y = q.y; v.z = q.z; v.w = q.w;
    __builtin_nontemporal_store(v, (vfloat4*)p);
}

__global__ void vq_zero(float* __restrict__ acc) {
    int i = blockIdx.x * blockDim.x + threadIdx.x;
    if (i < PSTR + NSLICE) acc[FINAL_OFF + i] = 0.0f;
}

// ---- Kernel 1: compute (per-thread) + emit (per-wave, coalesced, NT stores) ----
__global__ __launch_bounds__(TPB, 4) void vq_main(
    const float* __restrict__ z_e, const float* __restrict__ cb,
    float* __restrict__ o_soft, float* __restrict__ o_hard,
    float* __restrict__ o_idx, float* __restrict__ o_w,
    float* __restrict__ acc)
{
    __shared__ float cb_s[KC][CBS];
    __shared__ float wn_s[KC];
    __shared__ float w_s[4][64][WSTR];
    __shared__ int   idx_s[TPB];

    const int tid = threadIdx.x;
    const int wv  = tid >> 6;
    const int l   = tid & 63;

    #pragma unroll 1
    for (int i = tid; i < KC * DC; i += TPB)
        cb_s[i >> 7][i & (DC - 1)] = cb[i];
    __syncthreads();
    if (tid < KC) {
        float s = 0.0f;
        #pragma unroll 1
        for (int d = 0; d < DC; ++d) s = fmaf(cb_s[tid][d], cb_s[tid][d], s);
        wn_s[tid] = s;
    }
    __syncthreads();

    const int row = blockIdx.x * TPB + tid;
    const float* zp = z_e + (size_t)row * DC;

    // ---- Phase 1: per-thread distances/argmin/softmax ----
    float dv[KC];
    #pragma unroll
    for (int k = 0; k < KC; ++k) dv[k] = 0.0f;
    float zn = 0.0f;

    #pragma unroll 2
    for (int c = 0; c < 4; ++c) {
        float4 a[8];
        #pragma unroll
        for (int i = 0; i < 8; ++i)
            a[i] = *(const float4*)(zp + c * 32 + 4 * i);
        #pragma unroll
        for (int i = 0; i < 8; ++i)
            zn = fmaf(a[i].x, a[i].x, fmaf(a[i].y, a[i].y,
                 fmaf(a[i].z, a[i].z, fmaf(a[i].w, a[i].w, zn))));
        #pragma unroll
        for (int k = 0; k < KC; ++k) {
            float s = dv[k];
            #pragma unroll
            for (int i = 0; i < 8; ++i) {
                const float4 wvv = *(const float4*)(&cb_s[k][c * 32 + 4 * i]);
                s = fmaf(a[i].x, wvv.x, fmaf(a[i].y, wvv.y,
                    fmaf(a[i].z, wvv.z, fmaf(a[i].w, wvv.w, s))));
            }
            dv[k] = s;
        }
    }

    int idx = 0;
    float best = 3.4e38f;
    #pragma unroll
    for (int k = 0; k < KC; ++k) {
        float d = (zn - 2.0f * dv[k]) + wn_s[k];
        dv[k] = d;
        if (d < best) { best = d; idx = k; }
    }
    float ssum = 0.0f;
    #pragma unroll
    for (int k = 0; k < KC; ++k) {
        float e = __expf(best - dv[k]);
        dv[k] = e;
        ssum += e;
    }
    const float inv = 1.0f / ssum;
    #pragma unroll
    for (int k = 0; k < KC; ++k) dv[k] *= inv;   // weights

    // stage weights + idx for the emit phase
    #pragma unroll
    for (int q = 0; q < 6; ++q)
        *(float4*)(&w_s[wv][l][4 * q]) =
            make_float4(dv[4*q], dv[4*q+1], dv[4*q+2], dv[4*q+3]);
    idx_s[tid] = idx;
    o_idx[row] = (float)idx;                      // coalesced

    {
        float loss_acc = best;   // min-dist identity
        #pragma unroll
        for (int off = 32; off > 0; off >>= 1)
            loss_acc += __shfl_down(loss_acc, off);
        if (l == 0)
            atomicAdd(acc + LOSS_OFF + (blockIdx.x & (NSLICE - 1)), loss_acc);
    }
    __syncthreads();

    // ---- Phase 2: per-wave emit, lane-consecutive, nontemporal ----
    const int base2 = blockIdx.x * TPB + wv * 64;   // wave's first row
    const int d2 = 2 * l;
    float2 cbr[KC];
    #pragma unroll
    for (int k = 0; k < KC; ++k)
        cbr[k] = *(const float2*)(&cb_s[k][d2]);

    #pragma unroll 2
    for (int j = 0; j < 64; ++j) {
        const int r = base2 + j;
        const int ic = idx_s[wv * 64 + j];
        float wk[KC];
        #pragma unroll
        for (int q = 0; q < 6; ++q) {
            const float4 wq = *(const float4*)(&w_s[wv][j][4 * q]);  // uniform
            wk[4*q+0] = wq.x; wk[4*q+1] = wq.y;
            wk[4*q+2] = wq.z; wk[4*q+3] = wq.w;
        }
        float q0 = 0.0f, q1 = 0.0f;
        #pragma unroll
        for (int k = 0; k < KC; ++k) {
            q0 = fmaf(wk[k], cbr[k].x, q0);
            q1 = fmaf(wk[k], cbr[k].y, q1);
        }
        nt_store2(o_soft + (size_t)r * DC + d2, q0, q1);
        const float2 h2 = *(const float2*)(&cb_s[ic][d2]);
        nt_store2(o_hard + (size_t)r * DC + d2, h2.x, h2.y);
    }

    // weights out: 6 coalesced float4 per wave (nontemporal)
    #pragma unroll
    for (int i = 0; i < 6; ++i) {
        const int fo = i * 64 + l;
        const int jr = fo / 6, c = fo % 6;
        const float4 v = *(const float4*)(&w_s[wv][jr][4 * c]);
        nt_store4(o_w + (size_t)base2 * KC + 4 * fo, v);
    }
}

// ---- Kernel 2: ebin — wave-private LDS bins, non-atomic RMW, 16-deep MLP ----
__global__ __launch_bounds__(TPB) void vq_ebin(
    const float* __restrict__ z_e, const float* __restrict__ o_idx,
    float* __restrict__ acc)
{
    __shared__ float eb[4][KC][DC];    // 48 KB: wave-private bins
    __shared__ float cnt_sh[4][KC];

    const int tid = threadIdx.x;
    const int w   = tid >> 6;
    const int l   = tid & 63;
    const int d2  = 2 * l;

    #pragma unroll 1
    for (int i = l; i < KC * DC / 2; i += 64)
        ((float2*)&eb[w][0][0])[i] = make_float2(0.0f, 0.0f);
    if (l < KC) cnt_sh[w][l] = 0.0f;

    const int r0 = blockIdx.x * ROWS_PER_EBIN + w * (ROWS_PER_EBIN / 4);

    #pragma unroll 1
    for (int rb = 0; rb < ROWS_PER_EBIN / 4; rb += 16) {
        float2 v[16];
        float  fid[16];
        #pragma unroll
        for (int j = 0; j < 16; ++j)
            v[j] = *(const float2*)(z_e + (size_t)(r0 + rb + j) * DC + d2);
        #pragma unroll
        for (int j = 0; j < 16; ++j)
            fid[j] = o_idx[r0 + rb + j];
        #pragma unroll
        for (int j = 0; j < 16; ++j) {
            const int ic = (int)fid[j];
            float2 cur = *(float2*)(&eb[w][ic][d2]);    // wave-uniform row
            cur.x += v[j].x;
            cur.y += v[j].y;
            *(float2*)(&eb[w][ic][d2]) = cur;
            if (l == 0) cnt_sh[w][ic] += 1.0f;
        }
    }
    __syncthreads();

    float* part = acc + (size_t)blockIdx.x * PSTR;
    #pragma unroll 1
    for (int i = tid; i < KC * DC; i += TPB) {
        const int k = i >> 7, d = i & (DC - 1);
        part[i] = (eb[0][k][d] + eb[1][k][d]) + (eb[2][k][d] + eb[3][k][d]);
    }
    if (tid < KC)
        part[KC * DC + tid] = (cnt_sh[0][tid] + cnt_sh[1][tid])
                            + (cnt_sh[2][tid] + cnt_sh[3][tid]);
}

// ---- Kernel 3: reduce partials (parallel over b-chunks) ----
__global__ void vq_reduce(float* __restrict__ acc) {
    const int i = blockIdx.x * blockDim.x + threadIdx.x;
    if (i >= KC * DC + KC) return;
    const int b0 = blockIdx.y * RB;
    float s0 = 0.0f, s1 = 0.0f, s2 = 0.0f, s3 = 0.0f;
    #pragma unroll 2
    for (int b = b0; b < b0 + RB; b += 4) {
        s0 += acc[(size_t)(b + 0) * PSTR + i];
        s1 += acc[(size_t)(b + 1) * PSTR + i];
        s2 += acc[(size_t)(b + 2) * PSTR + i];
        s3 += acc[(size_t)(b + 3) * PSTR + i];
    }
    atomicAdd(&acc[FINAL_OFF + i], (s0 + s1) + (s2 + s3));
}

__global__ void vq_epilogue(
    const float* __restrict__ z_e, const float* __restrict__ ema_cs,
    const float* __restrict__ ema_es, const int* __restrict__ rand_idx,
    const float* __restrict__ acc,
    float* __restrict__ o_loss, float* __restrict__ o_cbn,
    float* __restrict__ o_ecs, float* __restrict__ o_ees)
{
    __shared__ float ecs_s[KC], sm_s[KC];
    __shared__ float n_sh;
    const int tid = threadIdx.x;
    const float* fin = acc + FINAL_OFF;
    if (tid < KC)
        ecs_s[tid] = 0.95f * ema_cs[tid] + 0.05f * fin[KC * DC + tid];
    __syncthreads();
    if (tid == 0) {
        float n = 0.0f;
        for (int k = 0; k < KC; ++k) n += ecs_s[k];
        n_sh = n;
    }
    __syncthreads();
    if (tid < KC) {
        float n = n_sh;
        sm_s[tid] = (ecs_s[tid] + 1e-5f) / (n + (float)KC * 1e-5f) * n;
    }
    __syncthreads();
    #pragma unroll 1
    for (int i = tid; i < KC * DC; i += TPB) {
        int k = i >> 7, d = i & (DC - 1);
        float ees = 0.95f * ema_es[i] + 0.05f * fin[i];
        float cbn = ees / sm_s[k];
        bool dead = ecs_s[k] < 0.1f;
        float rst = z_e[(size_t)rand_idx[k] * DC + d];
        o_cbn[i] = dead ? rst : cbn;
        o_ees[i] = dead ? rst : ees;
    }
    if (tid < KC) o_ecs[tid] = (ecs_s[tid] < 0.1f) ? 1.0f : ecs_s[tid];
    if (tid == 0) {
        float lsum = 0.0f;
        #pragma unroll
        for (int s = 0; s < NSLICE; ++s) lsum += acc[LOSS_OFF + s];
        o_loss[0] = 1.5f * (lsum * (1.0f / 67108864.0f));
    }
}

extern "C" void kernel_launch(void* const* d_in, const int* in_sizes, int n_in,
                              void* d_out, int out_size, void* d_ws, size_t ws_size,
                              hipStream_t stream) {
    const float* z_e    = (const float*)d_in[0];
    const float* cb     = (const float*)d_in[1];
    const float* ema_cs = (const float*)d_in[2];
    const float* ema_es = (const float*)d_in[3];
    const int*   ridx   = (const int*)d_in[4];

    float* out = (float*)d_out;
    float* o_soft = out;                                  // 67108864
    float* o_hard = out + 67108864ll;                     // 67108864
    float* o_idx  = out + 134217728ll;                    // 524288
    float* o_w    = out + 134742016ll;                    // 12582912
    float* o_loss = out + 147324928ll;                    // 1
    float* o_cbn  = out + 147324929ll;                    // 3072
    float* o_ecs  = out + 147328001ll;                    // 24
    float* o_ees  = out + 147328025ll;                    // 3072

    float* acc = (float*)d_ws;

    vq_zero<<<(PSTR + NSLICE + TPB - 1) / TPB, TPB, 0, stream>>>(acc);
    vq_main<<<NROWS / TPB, TPB, 0, stream>>>(
        z_e, cb, o_soft, o_hard, o_idx, o_w, acc);
    vq_ebin<<<NB_EBIN, TPB, 0, stream>>>(z_e, o_idx, acc);
    {
        dim3 g((KC * DC + KC + TPB - 1) / TPB, NB_EBIN / RB);
        vq_reduce<<<g, TPB, 0, stream>>>(acc);
    }
    vq_epilogue<<<1, TPB, 0, stream>>>(
        z_e, ema_cs, ema_es, ridx, acc, o_loss, o_cbn, o_ecs, o_ees);
}